// Round 10
// baseline (30843.008 us; speedup 1.0000x reference)
//
#include <hip/hip_runtime.h>
#include <cstdint>
#include <cstddef>

typedef unsigned short u16;
typedef unsigned int u32;
typedef float f32x4 __attribute__((ext_vector_type(4)));
typedef _Float16 f16x8 __attribute__((ext_vector_type(8)));
typedef _Float16 f16x2 __attribute__((ext_vector_type(2)));

__device__ __forceinline__ u16 f2h(float x) {
  _Float16 h = (_Float16)x;
  return __builtin_bit_cast(u16, h);
}
__device__ __forceinline__ float sigm(float x) { return 1.f / (1.f + __expf(-x)); }

__device__ __forceinline__ void gll16(const void* g, void* l) {
  __builtin_amdgcn_global_load_lds(
      (const __attribute__((address_space(1))) void*)g,
      (__attribute__((address_space(3))) void*)l, 16, 0, 0);
}

// 8-elem fp16 dot with f32 accumulate: exactly 4 v_dot2_f32_f16.
__device__ __forceinline__ float dot8(f16x8 a, f16x8 b, float acc) {
  union U { f16x8 v; f16x2 h[4]; };
  U ua, ub;
  ua.v = a;
  ub.v = b;
#if __has_builtin(__builtin_amdgcn_fdot2)
#pragma unroll
  for (int i = 0; i < 4; ++i)
    acc = __builtin_amdgcn_fdot2(ua.h[i], ub.h[i], acc, false);
#else
#pragma unroll
  for (int i = 0; i < 8; ++i) acc += (float)a[i] * (float)b[i];
#endif
  return acc;
}

enum { M_PLAIN = 0, M_TANH = 1, M_FC2 = 3 };

struct GemmP {
  const u16* A; int lda;
  const u16* W; int ldw;
  int K;                   // multiple of 64
  const float* bias;
  int mode;
  int czero;               // CELL: treat c_prev as 0
  u16* d0; int ld0;
  u16* d1; int ld1;
  float* c0;
  float* c1;
};

// ---- proven R6/R9 GEMM inner loop as a device function ----
// 512 thr = 8 waves (4 row x 2 col), tile 128x128, 4 LDS buffers, depth-2
// counted vmcnt, ONE s_barrier per K-step. CELL: i/f/g/o per (b,j) in one
// lane -> fused LSTM pointwise epilogue.
template <bool CELL>
__device__ __forceinline__ void gemm_dev(char* sm, const GemmP& p, int bx, int by) {
  const int tid = threadIdx.x;
  const int lane = tid & 63, wid = tid >> 6;
  const int wr = wid >> 1, wc = wid & 1;
  const int bRow = bx * 128;
  const int nBase = by * (CELL ? 32 : 128);
  const int col0 = lane & 15, g4 = lane >> 4;

  f32x4 acc[2][4];
#pragma unroll
  for (int m = 0; m < 2; ++m)
#pragma unroll
    for (int n = 0; n < 4; ++n) acc[m][n] = f32x4{0.f, 0.f, 0.f, 0.f};

  const char* Ab = (const char*)p.A;
  const char* Wb = (const char*)p.W;
  const size_t ldaB = (size_t)p.lda * 2, ldwB = (size_t)p.ldw * 2;

  auto stage = [&](int buf, int kt) {
    char* base = sm + buf * 32768;
    const int kb = kt * 128;
#pragma unroll
    for (int i = 0; i < 2; ++i) {
      const int s = i * 512 + tid;
      const int row = s >> 3, ch = s & 7;
      const int sch = ch ^ (row & 7);
      gll16(Ab + (size_t)(bRow + row) * ldaB + (size_t)(kb + sch * 16),
            base + s * 16);
      const int wrow = CELL ? ((row >> 5) * 1024 + nBase + (row & 31)) : (nBase + row);
      gll16(Wb + (size_t)wrow * ldwB + (size_t)(kb + sch * 16),
            base + 16384 + s * 16);
    }
  };

  const int nt = p.K >> 6;
  stage(0, 0);
  stage(1, 1);
  for (int t = 0; t < nt; ++t) {
    if (t + 2 < nt) stage((t + 2) & 3, t + 2);
    const int ahead = (nt - 1 - t < 2) ? (nt - 1 - t) : 2;
    if (ahead == 2)      asm volatile("s_waitcnt vmcnt(8)" ::: "memory");
    else if (ahead == 1) asm volatile("s_waitcnt vmcnt(4)" ::: "memory");
    else                 asm volatile("s_waitcnt vmcnt(0)" ::: "memory");
    __builtin_amdgcn_s_barrier();

    const char* Abase = sm + (t & 3) * 32768;
    const char* Wbase = Abase + 16384;
    f16x8 af[2][2], wf[2][4];
#pragma unroll
    for (int kf = 0; kf < 2; ++kf) {
      const int ch = kf * 4 + g4;
#pragma unroll
      for (int m = 0; m < 2; ++m) {
        const int r = wr * 32 + m * 16 + col0;
        af[kf][m] = *(const f16x8*)(Abase + r * 128 + ((ch ^ (r & 7)) << 4));
      }
#pragma unroll
      for (int n = 0; n < 4; ++n) {
        const int r = CELL ? (n * 32 + wc * 16 + col0) : (wc * 64 + n * 16 + col0);
        wf[kf][n] = *(const f16x8*)(Wbase + r * 128 + ((ch ^ (r & 7)) << 4));
      }
    }
#pragma unroll
    for (int kf = 0; kf < 2; ++kf)
#pragma unroll
      for (int m = 0; m < 2; ++m)
#pragma unroll
        for (int n = 0; n < 4; ++n)
          acc[m][n] = __builtin_amdgcn_mfma_f32_16x16x32_f16(af[kf][m], wf[kf][n],
                                                             acc[m][n], 0, 0, 0);
  }

  if (CELL) {
    const int j = nBase + wc * 16 + col0;
    const float bi = p.bias[j], bf_ = p.bias[j + 1024];
    const float bg = p.bias[j + 2048], bo = p.bias[j + 3072];
#pragma unroll
    for (int m = 0; m < 2; ++m) {
#pragma unroll
      for (int r = 0; r < 4; ++r) {
        const int b = bRow + wr * 32 + m * 16 + g4 * 4 + r;
        const float gi = acc[m][0][r] + bi;
        const float gf = acc[m][1][r] + bf_;
        const float gg = acc[m][2][r] + bg;
        const float go = acc[m][3][r] + bo;
        const size_t ci = (size_t)b * 1024 + j;
        const float cprev = p.czero ? 0.f : p.c0[ci];
        const float cn = sigm(gf) * cprev + sigm(gi) * tanhf(gg);
        p.c0[ci] = cn;
        const u16 hv = f2h(sigm(go) * tanhf(cn));
        p.d0[(size_t)b * p.ld0 + j] = hv;
        if (p.d1) p.d1[(size_t)b * p.ld1 + j] = hv;
      }
    }
  } else {
#pragma unroll
    for (int m = 0; m < 2; ++m)
#pragma unroll
      for (int n = 0; n < 4; ++n)
#pragma unroll
        for (int r = 0; r < 4; ++r) {
          const int b = bRow + wr * 32 + m * 16 + g4 * 4 + r;
          const int j = nBase + wc * 64 + n * 16 + col0;
          float v = acc[m][n][r] + p.bias[j];
          if (p.mode == M_TANH) {
            v = tanhf(v);
            const u16 hv = f2h(v);
            p.d0[(size_t)b * p.ld0 + j] = hv;
            if (p.d1) p.d1[(size_t)b * p.ld1 + j] = hv;
            if (p.c0) p.c0[(size_t)b * 1024 + j] = v;
            if (p.c1) p.c1[(size_t)b * 1024 + j] = v;
          } else if (p.mode == M_PLAIN) {
            p.d0[(size_t)b * p.ld0 + j] = f2h(v);
          } else {  // M_FC2
            if (j < 512) p.d0[(size_t)b * p.ld0 + j] = f2h(v);
            else         p.d1[(size_t)b * p.ld1 + (j - 512)] = f2h(tanhf(v));
          }
        }
  }
}

// standalone wrapper (prologue Wfused GEMM only)
template <bool CELL>
__global__ __launch_bounds__(512, 2) void gk(GemmP p) {
  __shared__ __align__(16) char sm[131072];
  gemm_dev<CELL>(sm, p, blockIdx.x, blockIdx.y);
}

// out projection for mega: blocks 0..127, 8 A-rows each. A staged in LDS
// (16 KB, row-XOR chunk swizzle); lane = (row 0..7) x (colpair), waves 0-5
// give 48 colpairs (45 used). LDS reads: 8 distinct addrs spread over all
// 32 banks (conflict-free), broadcast across same-row lanes.
__device__ __forceinline__ void out_dev(char* smc, const u16* A, const u16* W,
                                        const float* bias, u16* pdst, float* fout) {
  const int tid = threadIdx.x;
  const int r0 = blockIdx.x * 8;
  const char* Ab = (const char*)A;
#pragma unroll
  for (int i = 0; i < 2; ++i) {
    const int s = i * 512 + tid;
    const int row = s >> 7, kc = s & 127;
    const int skc = kc ^ (row & 7);
    gll16(Ab + (size_t)(r0 + row) * 4096 + skc * 16, smc + s * 16);
  }
  asm volatile("s_waitcnt vmcnt(0)" ::: "memory");
  __builtin_amdgcn_s_barrier();
  const int w = tid >> 6, lane = tid & 63;
  const int cp = w * 8 + (lane & 7);
  if (w >= 6 || cp >= 45) return;
  const int row = lane >> 3;
  const char* Arow = smc + row * 2048;
  const int c0 = cp * 2;
  const f16x8* w0 = (const f16x8*)(W + (size_t)c0 * 1024);
  const f16x8* w1 = (const f16x8*)(W + (size_t)(c0 + 1) * 1024);
  float a0 = 0.f, a1 = 0.f;
#pragma unroll 8
  for (int k = 0; k < 128; ++k) {
    const f16x8 a = *(const f16x8*)(Arow + ((k ^ row) << 4));
    a0 = dot8(a, w0[k], a0);
    a1 = dot8(a, w1[k], a1);
  }
  const int b = r0 + row;
  const float v0 = a0 + bias[c0], v1 = a1 + bias[c0 + 1];
  pdst[(size_t)b * 1664 + c0] = f2h(v0);
  pdst[(size_t)b * 1664 + c0 + 1] = f2h(v1);
  fout[(size_t)b * 5760 + c0] = sigm(v0);
  fout[(size_t)b * 5760 + c0 + 1] = sigm(v1);
}

// device-wide barrier (256 blocks, all co-resident: 128 KB LDS forces
// 1 block/CU, grid == 256 CUs). Sense-reversing via generation counter.
// threadfence before arrive = release (drain stores + L2 writeback);
// threadfence after = acquire (invalidate stale per-XCD L2 lines).
// Timeout converts a (theoretically impossible) non-residency deadlock
// into a visible wrong answer instead of a hang.
__device__ __forceinline__ void gbar(int* cnt, int* gen, int k) {
  __syncthreads();
  __threadfence();
  if (threadIdx.x == 0) {
    if (__hip_atomic_fetch_add(cnt, 1, __ATOMIC_ACQ_REL, __HIP_MEMORY_SCOPE_AGENT) == 255) {
      __hip_atomic_store(cnt, 0, __ATOMIC_RELAXED, __HIP_MEMORY_SCOPE_AGENT);
      __hip_atomic_store(gen, k, __ATOMIC_RELEASE, __HIP_MEMORY_SCOPE_AGENT);
    } else {
      int guard = 0;
      while (__hip_atomic_load(gen, __ATOMIC_ACQUIRE, __HIP_MEMORY_SCOPE_AGENT) < k) {
        __builtin_amdgcn_s_sleep(8);
        if (++guard > 200000) break;  // ~20 ms safety valve
      }
    }
  }
  __syncthreads();
  __threadfence();
}

struct MegaP {
  const u16 *zh, *Wz, *Wc0, *Wc1, *Wfc2, *Wb0, *Wb1, *Wout;
  u16 *Xc0, *Xc1, *Xb0, *Xb1;
  float *cc0, *cc1, *cbb0, *cbb1;
  const float *bz, *bc0, *bc1, *bfc2, *bb0, *bb1, *bout;
  float* outp;
  int *cnt, *gen;
};

// the whole decode loop: 241 GEMM/out tasks separated by device barriers.
__global__ __launch_bounds__(512, 2) void mega(MegaP m) {
  __shared__ __align__(16) char sm[131072];
  const int bid = blockIdx.x;
  int bk = 0;

  // cell-task tile mapping (XCD-swizzled: each XCD owns 4 weight panels)
  const int xcd = bid & 7, idx = bid >> 3;
  const int cby = xcd * 4 + (idx >> 3);  // weight panel [0,32)
  const int cbx = idx & 7;               // row block [0,8)

  // T0: s0 = tanh(z @ Wz^T + bz) -> h1,h2 (fp16), c1,c2 (f32)
  if (bid < 64) {
    GemmP p{m.zh, 512, m.Wz, 512, 512, m.bz, M_TANH, 0,
            m.Xc0 + 512, 1536, m.Xc1 + 1024, 2048, m.cc0, m.cc1};
    gemm_dev<false>(sm, p, bid & 7, bid >> 3);
  }
  gbar(m.cnt, m.gen, ++bk);

#pragma unroll 1
  for (int t = 0; t < 16; ++t) {
    {  // conductor layer 0
      GemmP p{m.Xc0, 1536, m.Wc0, 1536, 1536, m.bc0, 0, 0,
              m.Xc0 + 512, 1536, m.Xc1, 2048, m.cc0, nullptr};
      gemm_dev<true>(sm, p, cbx, cby);
    }
    gbar(m.cnt, m.gen, ++bk);
    {  // conductor layer 1
      GemmP p{m.Xc1, 2048, m.Wc1, 2048, 2048, m.bc1, 0, 0,
              m.Xc1 + 1024, 2048, nullptr, 0, m.cc1, nullptr};
      gemm_dev<true>(sm, p, cbx, cby);
    }
    gbar(m.cnt, m.gen, ++bk);
    if (bid < 64) {  // fused fc1+cfc: cond_out -> Xc0, tanh emb -> Xb0
      GemmP p{m.Xc1 + 1024, 2048, m.Wfc2, 1024, 1024, m.bfc2, M_FC2, 0,
              m.Xc0, 1536, m.Xb0, 1664, nullptr, nullptr};
      gemm_dev<false>(sm, p, bid & 7, bid >> 3);
    }
    gbar(m.cnt, m.gen, ++bk);
#pragma unroll 1
    for (int s = 0; s < 4; ++s) {
      {  // bottom layer 0; s==0: h1=0 & c=0 -> K=640, czero
        GemmP p{m.Xb0, 1664, m.Wb0, 1664, s ? 1664 : 640, m.bb0, 0, s == 0,
                m.Xb0 + 640, 1664, m.Xb1, 2048, m.cbb0, nullptr};
        gemm_dev<true>(sm, p, cbx, cby);
      }
      gbar(m.cnt, m.gen, ++bk);
      {  // bottom layer 1; s==0: h2=0 & c=0 -> K=1024, czero
        GemmP p{m.Xb1, 2048, m.Wb1, 2048, s ? 2048 : 1024, m.bb1, 0, s == 0,
                m.Xb1 + 1024, 2048, nullptr, 0, m.cbb1, nullptr};
        gemm_dev<true>(sm, p, cbx, cby);
      }
      gbar(m.cnt, m.gen, ++bk);
      if (bid < 128)
        out_dev(sm, m.Xb1 + 1024, m.Wout, m.bout, m.Xb0 + 512,
                m.outp + (size_t)(t * 4 + s) * 90);
      gbar(m.cnt, m.gen, ++bk);
    }
  }
}

// ---- prologue kernels (unchanged from R9 except zero_init) ----

__global__ void pack_w(u16* dst, const float* a, int Ka, const float* b, int Kb,
                       int gap, int Kp, int srcRows) {
  const int r = blockIdx.y;
  const int c = blockIdx.x * 256 + threadIdx.x;
  if (c >= Kp) return;
  float v = 0.f;
  if (r < srcRows) {
    if (c < Ka) v = a[(size_t)r * Ka + c];
    else if (c >= Ka + gap && c < Ka + gap + Kb) v = b[(size_t)r * Kb + (c - Ka - gap)];
  }
  dst[(size_t)r * Kp + c] = f2h(v);
}

__global__ void pack_fc1T(u16* dst, const float* src) {
  const int idx = blockIdx.x * 256 + threadIdx.x;
  const int n = idx >> 9, j = idx & 511;
  dst[idx] = f2h(src[(size_t)j * 1024 + n]);
}

__global__ __launch_bounds__(256, 4) void bias_fused(float* bfc2, const float* cfc_w,
                                                     const float* fc1_b,
                                                     const float* cfc_b) {
  const int i = blockIdx.x * 4 + (threadIdx.x >> 6);
  const int lane = threadIdx.x & 63;
  const float4* wrow = (const float4*)(cfc_w + (size_t)i * 512);
  const float4* bv = (const float4*)fc1_b;
  float s = 0.f;
#pragma unroll
  for (int q = 0; q < 2; ++q) {
    const float4 a = wrow[lane * 2 + q], b = bv[lane * 2 + q];
    s += a.x * b.x + a.y * b.y + a.z * b.z + a.w * b.w;
  }
#pragma unroll
  for (int off = 32; off; off >>= 1) s += __shfl_xor(s, off);
  if (lane == 0) bfc2[512 + i] = s + cfc_b[i];
}

struct BiasAll {
  float *bz, *bc0, *bc1, *bfc2, *bb0, *bb1, *bout, *bzero;
  const float *fzb, *ci0, *ch0, *ci1, *ch1, *f1b, *bi0, *bh0, *bi1, *bh1, *ob;
};
__global__ void pack_biases(BiasAll q) {
  int i = blockIdx.x * 256 + threadIdx.x;
  if (i < 1024) { q.bz[i] = q.fzb[i]; return; } i -= 1024;
  if (i < 4096) { q.bc0[i] = q.ci0[i] + q.ch0[i]; return; } i -= 4096;
  if (i < 4096) { q.bc1[i] = q.ci1[i] + q.ch1[i]; return; } i -= 4096;
  if (i < 512)  { q.bfc2[i] = q.f1b[i]; return; } i -= 512;
  if (i < 4096) { q.bb0[i] = q.bi0[i] + q.bh0[i]; return; } i -= 4096;
  if (i < 4096) { q.bb1[i] = q.bi1[i] + q.bh1[i]; return; } i -= 4096;
  if (i < 128)  { q.bout[i] = (i < 90) ? q.ob[i] : 0.f; return; } i -= 128;
  if (i < 1024) { q.bzero[i] = 0.f; }
}

__global__ void conv_h(u16* dst, const float* src, long n) {
  for (long i = (long)blockIdx.x * blockDim.x + threadIdx.x; i < n;
       i += (long)gridDim.x * blockDim.x)
    dst[i] = f2h(src[i]);
}

// zero Xc0 cols 0:512, Xb0 cols 512:640 (p slot + pad), and the mega
// barrier state (cnt, gen) -- MUST reset every call for determinism.
__global__ void zero_init(u32* xc0, u32* xb0, int* bar) {
  if (blockIdx.x == 0 && threadIdx.x < 2) bar[threadIdx.x] = 0;
  const int i = blockIdx.x * 256 + threadIdx.x;
  if (i < 1024 * 256) {
    xc0[(i >> 8) * 768 + (i & 255)] = 0;
  } else {
    const int k = i - 1024 * 256;
    xb0[(k >> 6) * 832 + 256 + (k & 63)] = 0;
  }
}

extern "C" void kernel_launch(void* const* d_in, const int* in_sizes, int n_in,
                              void* d_out, int out_size, void* d_ws, size_t ws_size,
                              hipStream_t stream) {
  const float* z      = (const float*)d_in[0];
  const float* fc_z_w = (const float*)d_in[2];
  const float* fc_z_b = (const float*)d_in[3];
  const float* cWih0  = (const float*)d_in[4];
  const float* cWhh0  = (const float*)d_in[5];
  const float* cbih0  = (const float*)d_in[6];
  const float* cbhh0  = (const float*)d_in[7];
  const float* cWih1  = (const float*)d_in[8];
  const float* cWhh1  = (const float*)d_in[9];
  const float* cbih1  = (const float*)d_in[10];
  const float* cbhh1  = (const float*)d_in[11];
  const float* fc1_w  = (const float*)d_in[12];
  const float* fc1_b  = (const float*)d_in[13];
  const float* cfc_w  = (const float*)d_in[14];
  const float* cfc_b  = (const float*)d_in[15];
  const float* bWih0  = (const float*)d_in[16];
  const float* bWhh0  = (const float*)d_in[17];
  const float* bbih0  = (const float*)d_in[18];
  const float* bbhh0  = (const float*)d_in[19];
  const float* bWih1  = (const float*)d_in[20];
  const float* bWhh1  = (const float*)d_in[21];
  const float* bbih1  = (const float*)d_in[22];
  const float* bbhh1  = (const float*)d_in[23];
  const float* out_w  = (const float*)d_in[24];
  const float* out_b  = (const float*)d_in[25];
  float* outp = (float*)d_out;

  char* w = (char*)d_ws;
  auto alloc = [&](size_t bytes) {
    char* p = w;
    w += (bytes + 255) & ~(size_t)255;
    return p;
  };
  u16* Wz    = (u16*)alloc((size_t)1024 * 512 * 2);
  u16* Wc0   = (u16*)alloc((size_t)4096 * 1536 * 2);
  u16* Wc1   = (u16*)alloc((size_t)4096 * 2048 * 2);
  u16* Wb0   = (u16*)alloc((size_t)4096 * 1664 * 2);
  u16* Wb1   = (u16*)alloc((size_t)4096 * 2048 * 2);
  u16* Wfc2  = (u16*)alloc((size_t)1024 * 1024 * 2);
  u16* Wcfc  = (u16*)alloc((size_t)512 * 512 * 2);
  u16* fc1T  = (u16*)alloc((size_t)1024 * 512 * 2);
  u16* Wout  = (u16*)alloc((size_t)128 * 1024 * 2);
  u16* zh    = (u16*)alloc((size_t)1024 * 512 * 2);
  u16* Xc0   = (u16*)alloc((size_t)1024 * 1536 * 2);
  u16* Xc1   = (u16*)alloc((size_t)1024 * 2048 * 2);
  u16* Xb0   = (u16*)alloc((size_t)1024 * 1664 * 2);
  u16* Xb1   = (u16*)alloc((size_t)1024 * 2048 * 2);
  float* cc0  = (float*)alloc((size_t)1024 * 1024 * 4);
  float* cc1  = (float*)alloc((size_t)1024 * 1024 * 4);
  float* cbb0 = (float*)alloc((size_t)1024 * 1024 * 4);
  float* cbb1 = (float*)alloc((size_t)1024 * 1024 * 4);
  float* bz   = (float*)alloc(1024 * 4);
  float* bc0  = (float*)alloc(4096 * 4);
  float* bc1  = (float*)alloc(4096 * 4);
  float* bfc2 = (float*)alloc(1024 * 4);
  float* bb0  = (float*)alloc(4096 * 4);
  float* bb1  = (float*)alloc(4096 * 4);
  float* bout = (float*)alloc(128 * 4);
  float* bzero= (float*)alloc(1024 * 4);
  int*   bar  = (int*)alloc(256);

  const dim3 blk(256), blk5(512);

  // --- prologue: pack weights/biases, init state, fused fc1->cfc ---
  pack_w<<<dim3(2, 1024), blk, 0, stream>>>(Wz,   fc_z_w, 512,  nullptr, 0,    0,  512,  1024);
  pack_w<<<dim3(6, 4096), blk, 0, stream>>>(Wc0,  cWih0,  512,  cWhh0,   1024, 0,  1536, 4096);
  pack_w<<<dim3(8, 4096), blk, 0, stream>>>(Wc1,  cWih1,  1024, cWhh1,   1024, 0,  2048, 4096);
  pack_w<<<dim3(7, 4096), blk, 0, stream>>>(Wb0,  bWih0,  602,  bWhh0,   1024, 38, 1664, 4096);
  pack_w<<<dim3(8, 4096), blk, 0, stream>>>(Wb1,  bWih1,  1024, bWhh1,   1024, 0,  2048, 4096);
  pack_w<<<dim3(4, 512),  blk, 0, stream>>>(Wfc2, fc1_w,  1024, nullptr, 0,    0,  1024, 512);
  pack_w<<<dim3(2, 512),  blk, 0, stream>>>(Wcfc, cfc_w,  512,  nullptr, 0,    0,  512,  512);
  pack_w<<<dim3(4, 128),  blk, 0, stream>>>(Wout, out_w,  1024, nullptr, 0,    0,  1024, 90);
  pack_fc1T<<<dim3(2048), blk, 0, stream>>>(fc1T, fc1_w);
  {
    BiasAll q{bz, bc0, bc1, bfc2, bb0, bb1, bout, bzero,
              fc_z_b, cbih0, cbhh0, cbih1, cbhh1, fc1_b,
              bbih0, bbhh0, bbih1, bbhh1, out_b};
    pack_biases<<<dim3(80), blk, 0, stream>>>(q);
  }
  bias_fused<<<dim3(128), blk, 0, stream>>>(bfc2, cfc_w, fc1_b, cfc_b);
  conv_h<<<dim3(512), blk, 0, stream>>>(zh, z, 1024L * 512);
  zero_init<<<dim3(1280), blk, 0, stream>>>((u32*)Xc0, (u32*)Xb0, bar);
  {  // Wfused = cfc_w @ fc1_w -> Wfc2 rows 512:1024
    GemmP p{Wcfc, 512, fc1T, 512, 512, bzero, M_PLAIN, 0,
            Wfc2 + (size_t)512 * 1024, 1024, nullptr, 0, nullptr, nullptr};
    gk<false><<<dim3(4, 8), blk5, 0, stream>>>(p);
  }

  // --- the entire decode loop in ONE launch (241 barrier-separated tasks) ---
  MegaP mp{zh, Wz, Wc0, Wc1, Wfc2, Wb0, Wb1, Wout,
           Xc0, Xc1, Xb0, Xb1,
           cc0, cc1, cbb0, cbb1,
           bz, bc0, bc1, bfc2, bb0, bb1, bout,
           outp, bar, bar + 1};
  mega<<<dim3(256), blk5, 0, stream>>>(mp);
}

// Round 11
// 17786.179 us; speedup vs baseline: 1.7341x; 1.7341x over previous
//
#include <hip/hip_runtime.h>
#include <cstdint>
#include <cstddef>

typedef unsigned short u16;
typedef unsigned int u32;
typedef float f32x4 __attribute__((ext_vector_type(4)));
typedef _Float16 f16x8 __attribute__((ext_vector_type(8)));
typedef _Float16 f16x2 __attribute__((ext_vector_type(2)));

__device__ __forceinline__ u16 f2h(float x) {
  _Float16 h = (_Float16)x;
  return __builtin_bit_cast(u16, h);
}
__device__ __forceinline__ float sigm(float x) { return 1.f / (1.f + __expf(-x)); }

__device__ __forceinline__ void gll16(const void* g, void* l) {
  __builtin_amdgcn_global_load_lds(
      (const __attribute__((address_space(1))) void*)g,
      (__attribute__((address_space(3))) void*)l, 16, 0, 0);
}

// 8-elem fp16 dot with f32 accumulate: exactly 4 v_dot2_f32_f16.
__device__ __forceinline__ float dot8(f16x8 a, f16x8 b, float acc) {
  union U { f16x8 v; f16x2 h[4]; };
  U ua, ub;
  ua.v = a;
  ub.v = b;
#if __has_builtin(__builtin_amdgcn_fdot2)
#pragma unroll
  for (int i = 0; i < 4; ++i)
    acc = __builtin_amdgcn_fdot2(ua.h[i], ub.h[i], acc, false);
#else
#pragma unroll
  for (int i = 0; i < 8; ++i) acc += (float)a[i] * (float)b[i];
#endif
  return acc;
}

enum { M_PLAIN = 0, M_TANH = 1, M_FC2 = 3 };

struct GemmP {
  const u16* A; int lda;
  const u16* W; int ldw;
  int K;                   // multiple of 64
  const float* bias;
  int mode;
  int czero;               // CELL: treat c_prev as 0
  u16* d0; int ld0;
  u16* d1; int ld1;
  float* c0;
  float* c1;
};

// ---- proven R6/R9 GEMM inner loop as a device function ----
// 512 thr = 8 waves (4 row x 2 col), tile 128x128, 4 LDS buffers, depth-2
// counted vmcnt, ONE s_barrier per K-step. CELL: i/f/g/o per (b,j) in one
// lane -> fused LSTM pointwise epilogue.
template <bool CELL>
__device__ __forceinline__ void gemm_dev(char* sm, const GemmP& p, int bx, int by) {
  const int tid = threadIdx.x;
  const int lane = tid & 63, wid = tid >> 6;
  const int wr = wid >> 1, wc = wid & 1;
  const int bRow = bx * 128;
  const int nBase = by * (CELL ? 32 : 128);
  const int col0 = lane & 15, g4 = lane >> 4;

  f32x4 acc[2][4];
#pragma unroll
  for (int m = 0; m < 2; ++m)
#pragma unroll
    for (int n = 0; n < 4; ++n) acc[m][n] = f32x4{0.f, 0.f, 0.f, 0.f};

  const char* Ab = (const char*)p.A;
  const char* Wb = (const char*)p.W;
  const size_t ldaB = (size_t)p.lda * 2, ldwB = (size_t)p.ldw * 2;

  auto stage = [&](int buf, int kt) {
    char* base = sm + buf * 32768;
    const int kb = kt * 128;
#pragma unroll
    for (int i = 0; i < 2; ++i) {
      const int s = i * 512 + tid;
      const int row = s >> 3, ch = s & 7;
      const int sch = ch ^ (row & 7);
      gll16(Ab + (size_t)(bRow + row) * ldaB + (size_t)(kb + sch * 16),
            base + s * 16);
      const int wrow = CELL ? ((row >> 5) * 1024 + nBase + (row & 31)) : (nBase + row);
      gll16(Wb + (size_t)wrow * ldwB + (size_t)(kb + sch * 16),
            base + 16384 + s * 16);
    }
  };

  const int nt = p.K >> 6;
  stage(0, 0);
  stage(1, 1);
  for (int t = 0; t < nt; ++t) {
    if (t + 2 < nt) stage((t + 2) & 3, t + 2);
    const int ahead = (nt - 1 - t < 2) ? (nt - 1 - t) : 2;
    if (ahead == 2)      asm volatile("s_waitcnt vmcnt(8)" ::: "memory");
    else if (ahead == 1) asm volatile("s_waitcnt vmcnt(4)" ::: "memory");
    else                 asm volatile("s_waitcnt vmcnt(0)" ::: "memory");
    __builtin_amdgcn_s_barrier();

    const char* Abase = sm + (t & 3) * 32768;
    const char* Wbase = Abase + 16384;
    f16x8 af[2][2], wf[2][4];
#pragma unroll
    for (int kf = 0; kf < 2; ++kf) {
      const int ch = kf * 4 + g4;
#pragma unroll
      for (int m = 0; m < 2; ++m) {
        const int r = wr * 32 + m * 16 + col0;
        af[kf][m] = *(const f16x8*)(Abase + r * 128 + ((ch ^ (r & 7)) << 4));
      }
#pragma unroll
      for (int n = 0; n < 4; ++n) {
        const int r = CELL ? (n * 32 + wc * 16 + col0) : (wc * 64 + n * 16 + col0);
        wf[kf][n] = *(const f16x8*)(Wbase + r * 128 + ((ch ^ (r & 7)) << 4));
      }
    }
#pragma unroll
    for (int kf = 0; kf < 2; ++kf)
#pragma unroll
      for (int m = 0; m < 2; ++m)
#pragma unroll
        for (int n = 0; n < 4; ++n)
          acc[m][n] = __builtin_amdgcn_mfma_f32_16x16x32_f16(af[kf][m], wf[kf][n],
                                                             acc[m][n], 0, 0, 0);
  }

  if (CELL) {
    const int j = nBase + wc * 16 + col0;
    const float bi = p.bias[j], bf_ = p.bias[j + 1024];
    const float bg = p.bias[j + 2048], bo = p.bias[j + 3072];
#pragma unroll
    for (int m = 0; m < 2; ++m) {
#pragma unroll
      for (int r = 0; r < 4; ++r) {
        const int b = bRow + wr * 32 + m * 16 + g4 * 4 + r;
        const float gi = acc[m][0][r] + bi;
        const float gf = acc[m][1][r] + bf_;
        const float gg = acc[m][2][r] + bg;
        const float go = acc[m][3][r] + bo;
        const size_t ci = (size_t)b * 1024 + j;
        const float cprev = p.czero ? 0.f : p.c0[ci];
        const float cn = sigm(gf) * cprev + sigm(gi) * tanhf(gg);
        p.c0[ci] = cn;
        const u16 hv = f2h(sigm(go) * tanhf(cn));
        p.d0[(size_t)b * p.ld0 + j] = hv;
        if (p.d1) p.d1[(size_t)b * p.ld1 + j] = hv;
      }
    }
  } else {
#pragma unroll
    for (int m = 0; m < 2; ++m)
#pragma unroll
      for (int n = 0; n < 4; ++n)
#pragma unroll
        for (int r = 0; r < 4; ++r) {
          const int b = bRow + wr * 32 + m * 16 + g4 * 4 + r;
          const int j = nBase + wc * 64 + n * 16 + col0;
          float v = acc[m][n][r] + p.bias[j];
          if (p.mode == M_TANH) {
            v = tanhf(v);
            const u16 hv = f2h(v);
            p.d0[(size_t)b * p.ld0 + j] = hv;
            if (p.d1) p.d1[(size_t)b * p.ld1 + j] = hv;
            if (p.c0) p.c0[(size_t)b * 1024 + j] = v;
            if (p.c1) p.c1[(size_t)b * 1024 + j] = v;
          } else if (p.mode == M_PLAIN) {
            p.d0[(size_t)b * p.ld0 + j] = f2h(v);
          } else {  // M_FC2
            if (j < 512) p.d0[(size_t)b * p.ld0 + j] = f2h(v);
            else         p.d1[(size_t)b * p.ld1 + (j - 512)] = f2h(tanhf(v));
          }
        }
  }
}

// standalone wrapper (prologue Wfused GEMM only)
template <bool CELL>
__global__ __launch_bounds__(512, 2) void gk(GemmP p) {
  __shared__ __align__(16) char sm[131072];
  gemm_dev<CELL>(sm, p, blockIdx.x, blockIdx.y);
}

// out projection for mega: blocks 0..127, 8 A-rows each. A staged in LDS
// (16 KB, row-XOR chunk swizzle); lane = (row 0..7) x (colpair), waves 0-5
// give 48 colpairs (45 used). LDS reads conflict-free (broadcast within row).
__device__ __forceinline__ void out_dev(char* smc, const u16* A, const u16* W,
                                        const float* bias, u16* pdst, float* fout) {
  const int tid = threadIdx.x;
  const int r0 = blockIdx.x * 8;
  const char* Ab = (const char*)A;
#pragma unroll
  for (int i = 0; i < 2; ++i) {
    const int s = i * 512 + tid;
    const int row = s >> 7, kc = s & 127;
    const int skc = kc ^ (row & 7);
    gll16(Ab + (size_t)(r0 + row) * 4096 + skc * 16, smc + s * 16);
  }
  asm volatile("s_waitcnt vmcnt(0)" ::: "memory");
  __builtin_amdgcn_s_barrier();
  const int w = tid >> 6, lane = tid & 63;
  const int cp = w * 8 + (lane & 7);
  if (w >= 6 || cp >= 45) return;
  const int row = lane >> 3;
  const char* Arow = smc + row * 2048;
  const int c0 = cp * 2;
  const f16x8* w0 = (const f16x8*)(W + (size_t)c0 * 1024);
  const f16x8* w1 = (const f16x8*)(W + (size_t)(c0 + 1) * 1024);
  float a0 = 0.f, a1 = 0.f;
#pragma unroll 8
  for (int k = 0; k < 128; ++k) {
    const f16x8 a = *(const f16x8*)(Arow + ((k ^ row) << 4));
    a0 = dot8(a, w0[k], a0);
    a1 = dot8(a, w1[k], a1);
  }
  const int b = r0 + row;
  const float v0 = a0 + bias[c0], v1 = a1 + bias[c0 + 1];
  pdst[(size_t)b * 1664 + c0] = f2h(v0);
  pdst[(size_t)b * 1664 + c0 + 1] = f2h(v1);
  fout[(size_t)b * 5760 + c0] = sigm(v0);
  fout[(size_t)b * 5760 + c0 + 1] = sigm(v1);
}

// device-wide barrier (256 blocks, all co-resident: 128 KB LDS forces
// 1 block/CU, grid == 256 CUs). Sense-reversing via generation counter.
//
// R10 LESSON (rocprof: MfmaUtil 2.9%, 4.3 GB HBM fetch, 128 us/barrier):
// polling with an ACQUIRE load at agent scope emits a cache-invalidate
// per poll -> 255 spinners x ~5 polls/us = an L2-invalidate storm that
// serialized at the TCC and evicted the weight panels every phase.
// Fix: RELAXED polling; ONE release fence before arrival (thread 0 --
// __syncthreads has already drained all waves' stores to L2) and ONE
// acquire fence after the wait (all threads, so per-CU L1s invalidate).
__device__ __forceinline__ void gbar(int* cnt, int* gen, int k) {
  __syncthreads();
  if (threadIdx.x == 0) {
    __threadfence();  // release: write back this XCD's dirty L2, once
    if (__hip_atomic_fetch_add(cnt, 1, __ATOMIC_RELAXED, __HIP_MEMORY_SCOPE_AGENT) == 255) {
      __hip_atomic_store(cnt, 0, __ATOMIC_RELAXED, __HIP_MEMORY_SCOPE_AGENT);
      __hip_atomic_store(gen, k, __ATOMIC_RELEASE, __HIP_MEMORY_SCOPE_AGENT);
    } else {
      int guard = 0;
      while (__hip_atomic_load(gen, __ATOMIC_RELAXED, __HIP_MEMORY_SCOPE_AGENT) < k) {
        __builtin_amdgcn_s_sleep(8);
        if (++guard > 200000) break;  // safety valve: visible fail, not hang
      }
    }
  }
  __syncthreads();
  __threadfence();  // acquire: invalidate stale lines once, after the wait
}

struct MegaP {
  const u16 *zh, *Wz, *Wc0, *Wc1, *Wfc2, *Wb0, *Wb1, *Wout;
  u16 *Xc0, *Xc1, *Xb0, *Xb1;
  float *cc0, *cc1, *cbb0, *cbb1;
  const float *bz, *bc0, *bc1, *bfc2, *bb0, *bb1, *bout;
  float* outp;
  int *cnt, *gen;
};

// the whole decode loop: 241 GEMM/out tasks separated by device barriers.
__global__ __launch_bounds__(512, 2) void mega(MegaP m) {
  __shared__ __align__(16) char sm[131072];
  const int bid = blockIdx.x;
  int bk = 0;

  // cell-task tile mapping (XCD-swizzled: each XCD owns 4 weight panels)
  const int xcd = bid & 7, idx = bid >> 3;
  const int cby = xcd * 4 + (idx >> 3);  // weight panel [0,32)
  const int cbx = idx & 7;               // row block [0,8)

  // T0: s0 = tanh(z @ Wz^T + bz) -> h1,h2 (fp16), c1,c2 (f32)
  if (bid < 64) {
    GemmP p{m.zh, 512, m.Wz, 512, 512, m.bz, M_TANH, 0,
            m.Xc0 + 512, 1536, m.Xc1 + 1024, 2048, m.cc0, m.cc1};
    gemm_dev<false>(sm, p, bid & 7, bid >> 3);
  }
  gbar(m.cnt, m.gen, ++bk);

#pragma unroll 1
  for (int t = 0; t < 16; ++t) {
    {  // conductor layer 0
      GemmP p{m.Xc0, 1536, m.Wc0, 1536, 1536, m.bc0, 0, 0,
              m.Xc0 + 512, 1536, m.Xc1, 2048, m.cc0, nullptr};
      gemm_dev<true>(sm, p, cbx, cby);
    }
    gbar(m.cnt, m.gen, ++bk);
    {  // conductor layer 1
      GemmP p{m.Xc1, 2048, m.Wc1, 2048, 2048, m.bc1, 0, 0,
              m.Xc1 + 1024, 2048, nullptr, 0, m.cc1, nullptr};
      gemm_dev<true>(sm, p, cbx, cby);
    }
    gbar(m.cnt, m.gen, ++bk);
    if (bid < 64) {  // fused fc1+cfc: cond_out -> Xc0, tanh emb -> Xb0
      GemmP p{m.Xc1 + 1024, 2048, m.Wfc2, 1024, 1024, m.bfc2, M_FC2, 0,
              m.Xc0, 1536, m.Xb0, 1664, nullptr, nullptr};
      gemm_dev<false>(sm, p, bid & 7, bid >> 3);
    }
    gbar(m.cnt, m.gen, ++bk);
#pragma unroll 1
    for (int s = 0; s < 4; ++s) {
      {  // bottom layer 0; s==0: h1=0 & c=0 -> K=640, czero
        GemmP p{m.Xb0, 1664, m.Wb0, 1664, s ? 1664 : 640, m.bb0, 0, s == 0,
                m.Xb0 + 640, 1664, m.Xb1, 2048, m.cbb0, nullptr};
        gemm_dev<true>(sm, p, cbx, cby);
      }
      gbar(m.cnt, m.gen, ++bk);
      {  // bottom layer 1; s==0: h2=0 & c=0 -> K=1024, czero
        GemmP p{m.Xb1, 2048, m.Wb1, 2048, s ? 2048 : 1024, m.bb1, 0, s == 0,
                m.Xb1 + 1024, 2048, nullptr, 0, m.cbb1, nullptr};
        gemm_dev<true>(sm, p, cbx, cby);
      }
      gbar(m.cnt, m.gen, ++bk);
      if (bid < 128)
        out_dev(sm, m.Xb1 + 1024, m.Wout, m.bout, m.Xb0 + 512,
                m.outp + (size_t)(t * 4 + s) * 90);
      gbar(m.cnt, m.gen, ++bk);
    }
  }
}

// ---- prologue kernels ----

__global__ void pack_w(u16* dst, const float* a, int Ka, const float* b, int Kb,
                       int gap, int Kp, int srcRows) {
  const int r = blockIdx.y;
  const int c = blockIdx.x * 256 + threadIdx.x;
  if (c >= Kp) return;
  float v = 0.f;
  if (r < srcRows) {
    if (c < Ka) v = a[(size_t)r * Ka + c];
    else if (c >= Ka + gap && c < Ka + gap + Kb) v = b[(size_t)r * Kb + (c - Ka - gap)];
  }
  dst[(size_t)r * Kp + c] = f2h(v);
}

__global__ void pack_fc1T(u16* dst, const float* src) {
  const int idx = blockIdx.x * 256 + threadIdx.x;
  const int n = idx >> 9, j = idx & 511;
  dst[idx] = f2h(src[(size_t)j * 1024 + n]);
}

__global__ __launch_bounds__(256, 4) void bias_fused(float* bfc2, const float* cfc_w,
                                                     const float* fc1_b,
                                                     const float* cfc_b) {
  const int i = blockIdx.x * 4 + (threadIdx.x >> 6);
  const int lane = threadIdx.x & 63;
  const float4* wrow = (const float4*)(cfc_w + (size_t)i * 512);
  const float4* bv = (const float4*)fc1_b;
  float s = 0.f;
#pragma unroll
  for (int q = 0; q < 2; ++q) {
    const float4 a = wrow[lane * 2 + q], b = bv[lane * 2 + q];
    s += a.x * b.x + a.y * b.y + a.z * b.z + a.w * b.w;
  }
#pragma unroll
  for (int off = 32; off; off >>= 1) s += __shfl_xor(s, off);
  if (lane == 0) bfc2[512 + i] = s + cfc_b[i];
}

struct BiasAll {
  float *bz, *bc0, *bc1, *bfc2, *bb0, *bb1, *bout, *bzero;
  const float *fzb, *ci0, *ch0, *ci1, *ch1, *f1b, *bi0, *bh0, *bi1, *bh1, *ob;
};
__global__ void pack_biases(BiasAll q) {
  int i = blockIdx.x * 256 + threadIdx.x;
  if (i < 1024) { q.bz[i] = q.fzb[i]; return; } i -= 1024;
  if (i < 4096) { q.bc0[i] = q.ci0[i] + q.ch0[i]; return; } i -= 4096;
  if (i < 4096) { q.bc1[i] = q.ci1[i] + q.ch1[i]; return; } i -= 4096;
  if (i < 512)  { q.bfc2[i] = q.f1b[i]; return; } i -= 512;
  if (i < 4096) { q.bb0[i] = q.bi0[i] + q.bh0[i]; return; } i -= 4096;
  if (i < 4096) { q.bb1[i] = q.bi1[i] + q.bh1[i]; return; } i -= 4096;
  if (i < 128)  { q.bout[i] = (i < 90) ? q.ob[i] : 0.f; return; } i -= 128;
  if (i < 1024) { q.bzero[i] = 0.f; }
}

__global__ void conv_h(u16* dst, const float* src, long n) {
  for (long i = (long)blockIdx.x * blockDim.x + threadIdx.x; i < n;
       i += (long)gridDim.x * blockDim.x)
    dst[i] = f2h(src[i]);
}

// zero Xc0 cols 0:512, Xb0 cols 512:640 (p slot + pad), and the mega
// barrier state (cnt, gen) -- MUST reset every call for determinism.
__global__ void zero_init(u32* xc0, u32* xb0, int* bar) {
  if (blockIdx.x == 0 && threadIdx.x < 2) bar[threadIdx.x] = 0;
  const int i = blockIdx.x * 256 + threadIdx.x;
  if (i < 1024 * 256) {
    xc0[(i >> 8) * 768 + (i & 255)] = 0;
  } else {
    const int k = i - 1024 * 256;
    xb0[(k >> 6) * 832 + 256 + (k & 63)] = 0;
  }
}

extern "C" void kernel_launch(void* const* d_in, const int* in_sizes, int n_in,
                              void* d_out, int out_size, void* d_ws, size_t ws_size,
                              hipStream_t stream) {
  const float* z      = (const float*)d_in[0];
  const float* fc_z_w = (const float*)d_in[2];
  const float* fc_z_b = (const float*)d_in[3];
  const float* cWih0  = (const float*)d_in[4];
  const float* cWhh0  = (const float*)d_in[5];
  const float* cbih0  = (const float*)d_in[6];
  const float* cbhh0  = (const float*)d_in[7];
  const float* cWih1  = (const float*)d_in[8];
  const float* cWhh1  = (const float*)d_in[9];
  const float* cbih1  = (const float*)d_in[10];
  const float* cbhh1  = (const float*)d_in[11];
  const float* fc1_w  = (const float*)d_in[12];
  const float* fc1_b  = (const float*)d_in[13];
  const float* cfc_w  = (const float*)d_in[14];
  const float* cfc_b  = (const float*)d_in[15];
  const float* bWih0  = (const float*)d_in[16];
  const float* bWhh0  = (const float*)d_in[17];
  const float* bbih0  = (const float*)d_in[18];
  const float* bbhh0  = (const float*)d_in[19];
  const float* bWih1  = (const float*)d_in[20];
  const float* bWhh1  = (const float*)d_in[21];
  const float* bbih1  = (const float*)d_in[22];
  const float* bbhh1  = (const float*)d_in[23];
  const float* out_w  = (const float*)d_in[24];
  const float* out_b  = (const float*)d_in[25];
  float* outp = (float*)d_out;

  char* w = (char*)d_ws;
  auto alloc = [&](size_t bytes) {
    char* p = w;
    w += (bytes + 255) & ~(size_t)255;
    return p;
  };
  u16* Wz    = (u16*)alloc((size_t)1024 * 512 * 2);
  u16* Wc0   = (u16*)alloc((size_t)4096 * 1536 * 2);
  u16* Wc1   = (u16*)alloc((size_t)4096 * 2048 * 2);
  u16* Wb0   = (u16*)alloc((size_t)4096 * 1664 * 2);
  u16* Wb1   = (u16*)alloc((size_t)4096 * 2048 * 2);
  u16* Wfc2  = (u16*)alloc((size_t)1024 * 1024 * 2);
  u16* Wcfc  = (u16*)alloc((size_t)512 * 512 * 2);
  u16* fc1T  = (u16*)alloc((size_t)1024 * 512 * 2);
  u16* Wout  = (u16*)alloc((size_t)128 * 1024 * 2);
  u16* zh    = (u16*)alloc((size_t)1024 * 512 * 2);
  u16* Xc0   = (u16*)alloc((size_t)1024 * 1536 * 2);
  u16* Xc1   = (u16*)alloc((size_t)1024 * 2048 * 2);
  u16* Xb0   = (u16*)alloc((size_t)1024 * 1664 * 2);
  u16* Xb1   = (u16*)alloc((size_t)1024 * 2048 * 2);
  float* cc0  = (float*)alloc((size_t)1024 * 1024 * 4);
  float* cc1  = (float*)alloc((size_t)1024 * 1024 * 4);
  float* cbb0 = (float*)alloc((size_t)1024 * 1024 * 4);
  float* cbb1 = (float*)alloc((size_t)1024 * 1024 * 4);
  float* bz   = (float*)alloc(1024 * 4);
  float* bc0  = (float*)alloc(4096 * 4);
  float* bc1  = (float*)alloc(4096 * 4);
  float* bfc2 = (float*)alloc(1024 * 4);
  float* bb0  = (float*)alloc(4096 * 4);
  float* bb1  = (float*)alloc(4096 * 4);
  float* bout = (float*)alloc(128 * 4);
  float* bzero= (float*)alloc(1024 * 4);
  int*   bar  = (int*)alloc(256);

  const dim3 blk(256), blk5(512);

  // --- prologue: pack weights/biases, init state, fused fc1->cfc ---
  pack_w<<<dim3(2, 1024), blk, 0, stream>>>(Wz,   fc_z_w, 512,  nullptr, 0,    0,  512,  1024);
  pack_w<<<dim3(6, 4096), blk, 0, stream>>>(Wc0,  cWih0,  512,  cWhh0,   1024, 0,  1536, 4096);
  pack_w<<<dim3(8, 4096), blk, 0, stream>>>(Wc1,  cWih1,  1024, cWhh1,   1024, 0,  2048, 4096);
  pack_w<<<dim3(7, 4096), blk, 0, stream>>>(Wb0,  bWih0,  602,  bWhh0,   1024, 38, 1664, 4096);
  pack_w<<<dim3(8, 4096), blk, 0, stream>>>(Wb1,  bWih1,  1024, bWhh1,   1024, 0,  2048, 4096);
  pack_w<<<dim3(4, 512),  blk, 0, stream>>>(Wfc2, fc1_w,  1024, nullptr, 0,    0,  1024, 512);
  pack_w<<<dim3(2, 512),  blk, 0, stream>>>(Wcfc, cfc_w,  512,  nullptr, 0,    0,  512,  512);
  pack_w<<<dim3(4, 128),  blk, 0, stream>>>(Wout, out_w,  1024, nullptr, 0,    0,  1024, 90);
  pack_fc1T<<<dim3(2048), blk, 0, stream>>>(fc1T, fc1_w);
  {
    BiasAll q{bz, bc0, bc1, bfc2, bb0, bb1, bout, bzero,
              fc_z_b, cbih0, cbhh0, cbih1, cbhh1, fc1_b,
              bbih0, bbhh0, bbih1, bbhh1, out_b};
    pack_biases<<<dim3(80), blk, 0, stream>>>(q);
  }
  bias_fused<<<dim3(128), blk, 0, stream>>>(bfc2, cfc_w, fc1_b, cfc_b);
  conv_h<<<dim3(512), blk, 0, stream>>>(zh, z, 1024L * 512);
  zero_init<<<dim3(1280), blk, 0, stream>>>((u32*)Xc0, (u32*)Xb0, bar);
  {  // Wfused = cfc_w @ fc1_w -> Wfc2 rows 512:1024
    GemmP p{Wcfc, 512, fc1T, 512, 512, bzero, M_PLAIN, 0,
            Wfc2 + (size_t)512 * 1024, 1024, nullptr, 0, nullptr, nullptr};
    gk<false><<<dim3(4, 8), blk5, 0, stream>>>(p);
  }

  // --- the entire decode loop in ONE launch (241 barrier-separated tasks) ---
  MegaP mp{zh, Wz, Wc0, Wc1, Wfc2, Wb0, Wb1, Wout,
           Xc0, Xc1, Xb0, Xb1,
           cc0, cc1, cbb0, cbb1,
           bz, bc0, bc1, bfc2, bb0, bb1, bout,
           outp, bar, bar + 1};
  mega<<<dim3(256), blk5, 0, stream>>>(mp);
}

// Round 12
// 6115.572 us; speedup vs baseline: 5.0434x; 2.9083x over previous
//
#include <hip/hip_runtime.h>
#include <cstdint>
#include <cstddef>

typedef unsigned short u16;
typedef unsigned int u32;
typedef float f32x4 __attribute__((ext_vector_type(4)));
typedef _Float16 f16x8 __attribute__((ext_vector_type(8)));
typedef _Float16 f16x2 __attribute__((ext_vector_type(2)));
typedef unsigned short u16x8 __attribute__((ext_vector_type(8)));

__device__ __forceinline__ u16 f2h(float x) {
  _Float16 h = (_Float16)x;
  return __builtin_bit_cast(u16, h);
}
__device__ __forceinline__ float sigm(float x) { return 1.f / (1.f + __expf(-x)); }

__device__ __forceinline__ void gll16(const void* g, void* l) {
  __builtin_amdgcn_global_load_lds(
      (const __attribute__((address_space(1))) void*)g,
      (__attribute__((address_space(3))) void*)l, 16, 0, 0);
}

// 8-elem fp16 dot with f32 accumulate: exactly 4 v_dot2_f32_f16.
__device__ __forceinline__ float dot8(f16x8 a, f16x8 b, float acc) {
  union U { f16x8 v; f16x2 h[4]; };
  U ua, ub;
  ua.v = a;
  ub.v = b;
#if __has_builtin(__builtin_amdgcn_fdot2)
#pragma unroll
  for (int i = 0; i < 4; ++i)
    acc = __builtin_amdgcn_fdot2(ua.h[i], ub.h[i], acc, false);
#else
#pragma unroll
  for (int i = 0; i < 8; ++i) acc += (float)a[i] * (float)b[i];
#endif
  return acc;
}

// ============ LSTM-cell GEMM, W direct-from-global (reg-staged) ============
// R11 diagnosis: the old kernel was LDS-pipe-bound (~12 ds_read_b128/thr/step
// ~ 1150cyc > 620cyc MFMA). Fix: weights pre-packed in per-lane MFMA fragment
// order -> each wave buffer_loads wf[2][4] straight to VGPRs (1KB coalesced,
// L2-resident, wfA/wfB static double-buffer). LDS stages only the A-tile:
// 4 ds_read + 2 gll per thread per step ~= 510cyc LDS < 620cyc MFMA.
// Counted vmcnt: steady outstanding = wf(t+1)8 + A(t+1)2 + A(t+2)2 = 12.
struct CellP {
  const u16* A; int lda;   // fp16 activations, row-major
  const u16* Wf;           // fragged weights [panel][t][wc][kf][n][lane]x16B
  int nt;                  // K/64 this pass (reduced-K for s==0)
  int ntFull;              // full panel stride in frag layout
  const float* bias;       // combined bias, gate-major [4][1024]
  int czero;               // treat c_prev as 0
  u16* d0; int ld0;
  u16* d1; int ld1;
  float* c0;
};

__global__ __launch_bounds__(512, 2) void ck(CellP p) {
  __shared__ __align__(16) char sm[65536];  // 4 x 16KB A-tile buffers
  const int tid = threadIdx.x;
  const int lane = tid & 63, wid = tid >> 6;
  const int wr = wid >> 1, wc = wid & 1;
  // XCD swizzle: each XCD owns 4 whole weight panels (8 row-blocks each)
  const int hw = blockIdx.x;
  const int xcd = hw & 7, idx = hw >> 3;
  const int by = xcd * 4 + (idx >> 3);  // panel [0,32)
  const int bx = idx & 7;               // row block [0,8)
  const int bRow = bx * 128;
  const int col0 = lane & 15, g4 = lane >> 4;
  const int nt = p.nt;

  f32x4 acc[2][4];
#pragma unroll
  for (int m = 0; m < 2; ++m)
#pragma unroll
    for (int n = 0; n < 4; ++n) acc[m][n] = f32x4{0.f, 0.f, 0.f, 0.f};

  const char* Ab = (const char*)p.A;
  const size_t ldaB = (size_t)p.lda * 2;

  // A-tile 128x64 -> LDS (linear dest; XOR chunk swizzle on global source,
  // undone on the ds_read side -- proven involution from R6).
  auto stageA = [&](int buf, int kt) {
    char* base = sm + buf * 16384;
    const int kb = kt * 128;
#pragma unroll
    for (int i = 0; i < 2; ++i) {
      const int s = i * 512 + tid;
      const int row = s >> 3, ch = s & 7;
      const int sch = ch ^ (row & 7);
      gll16(Ab + (size_t)(bRow + row) * ldaB + (size_t)(kb + sch * 16),
            base + s * 16);
    }
  };

  // W fragments: base for (by, wc); per t advance 16KB; 8 loads at imm offsets
  const char* Wfb = (const char*)p.Wf +
                    ((size_t)(by * p.ntFull) * 2 + wc) * 8192 + lane * 16;
  auto loadW = [&](f16x8 (&wf)[2][4], int kt) {
    const char* b = Wfb + (size_t)kt * 16384;
#pragma unroll
    for (int kf = 0; kf < 2; ++kf)
#pragma unroll
      for (int n = 0; n < 4; ++n)
        wf[kf][n] = *(const f16x8*)(b + (kf * 4 + n) * 1024);
  };

  auto step = [&](int u, const f16x8 (&wf)[2][4]) {
    const bool w1 = (u + 1 < nt), w2 = (u + 2 < nt);
    if (w1 && w2) asm volatile("s_waitcnt vmcnt(12)" ::: "memory");
    else if (w1)  asm volatile("s_waitcnt vmcnt(10)" ::: "memory");
    else          asm volatile("s_waitcnt vmcnt(0)" ::: "memory");
    __builtin_amdgcn_s_barrier();
    const char* Abase = sm + (u & 3) * 16384;
    f16x8 af[2][2];
#pragma unroll
    for (int kf = 0; kf < 2; ++kf) {
      const int ch = kf * 4 + g4;
#pragma unroll
      for (int m = 0; m < 2; ++m) {
        const int r = wr * 32 + m * 16 + col0;
        af[kf][m] = *(const f16x8*)(Abase + r * 128 + ((ch ^ (r & 7)) << 4));
      }
    }
#pragma unroll
    for (int kf = 0; kf < 2; ++kf)
#pragma unroll
      for (int m = 0; m < 2; ++m)
#pragma unroll
        for (int n = 0; n < 4; ++n)
          acc[m][n] = __builtin_amdgcn_mfma_f32_16x16x32_f16(af[kf][m], wf[kf][n],
                                                             acc[m][n], 0, 0, 0);
    // A-buffer reuse distance 4 + one barrier/step: race-free (R6-proven).
  };

  f16x8 wfA[2][4], wfB[2][4];
  stageA(0, 0);
  stageA(1, 1);
  loadW(wfA, 0);
  for (int t = 0; t < nt; t += 2) {        // nt is always even here
    if (t + 1 < nt) loadW(wfB, t + 1);
    if (t + 2 < nt) stageA((t + 2) & 3, t + 2);
    step(t, wfA);
    if (t + 1 >= nt) break;
    if (t + 2 < nt) loadW(wfA, t + 2);
    if (t + 3 < nt) stageA((t + 3) & 3, t + 3);
    step(t + 1, wfB);
  }

  // fused LSTM pointwise epilogue (i/f/g/o in one lane)
  const int j = by * 32 + wc * 16 + col0;
  const float bi = p.bias[j], bf_ = p.bias[j + 1024];
  const float bg = p.bias[j + 2048], bo = p.bias[j + 3072];
#pragma unroll
  for (int m = 0; m < 2; ++m) {
#pragma unroll
    for (int r = 0; r < 4; ++r) {
      const int b = bRow + wr * 32 + m * 16 + g4 * 4 + r;
      const float gi = acc[m][0][r] + bi;
      const float gf = acc[m][1][r] + bf_;
      const float gg = acc[m][2][r] + bg;
      const float go = acc[m][3][r] + bo;
      const size_t ci = (size_t)b * 1024 + j;
      const float cprev = p.czero ? 0.f : p.c0[ci];
      const float cn = sigm(gf) * cprev + sigm(gi) * tanhf(gg);
      p.c0[ci] = cn;
      const u16 hv = f2h(sigm(go) * tanhf(cn));
      p.d0[(size_t)b * p.ld0 + j] = hv;
      if (p.d1) p.d1[(size_t)b * p.ld1 + j] = hv;
    }
  }
}

// ============ generic 128x128 GEMM (R6-proven), non-cell tasks ============
enum { M_PLAIN = 0, M_TANH = 1, M_FC2 = 3 };

struct GemmP {
  const u16* A; int lda;
  const u16* W; int ldw;   // row-major [N, K]
  int K;
  const float* bias;
  int mode;
  u16* d0; int ld0;
  u16* d1; int ld1;
  float* c0;
  float* c1;
};

__global__ __launch_bounds__(512, 2) void gk(GemmP p) {
  __shared__ __align__(16) char sm[131072];  // 4 x (16K A + 16K W)
  const int tid = threadIdx.x;
  const int lane = tid & 63, wid = tid >> 6;
  const int wr = wid >> 1, wc = wid & 1;
  const int bRow = blockIdx.x * 128;
  const int nBase = blockIdx.y * 128;
  const int col0 = lane & 15, g4 = lane >> 4;

  f32x4 acc[2][4];
#pragma unroll
  for (int m = 0; m < 2; ++m)
#pragma unroll
    for (int n = 0; n < 4; ++n) acc[m][n] = f32x4{0.f, 0.f, 0.f, 0.f};

  const char* Ab = (const char*)p.A;
  const char* Wb = (const char*)p.W;
  const size_t ldaB = (size_t)p.lda * 2, ldwB = (size_t)p.ldw * 2;

  auto stage = [&](int buf, int kt) {
    char* base = sm + buf * 32768;
    const int kb = kt * 128;
#pragma unroll
    for (int i = 0; i < 2; ++i) {
      const int s = i * 512 + tid;
      const int row = s >> 3, ch = s & 7;
      const int sch = ch ^ (row & 7);
      gll16(Ab + (size_t)(bRow + row) * ldaB + (size_t)(kb + sch * 16),
            base + s * 16);
      gll16(Wb + (size_t)(nBase + row) * ldwB + (size_t)(kb + sch * 16),
            base + 16384 + s * 16);
    }
  };

  const int nt = p.K >> 6;
  stage(0, 0);
  stage(1, 1);
  for (int t = 0; t < nt; ++t) {
    if (t + 2 < nt) stage((t + 2) & 3, t + 2);
    const int ahead = (nt - 1 - t < 2) ? (nt - 1 - t) : 2;
    if (ahead == 2)      asm volatile("s_waitcnt vmcnt(8)" ::: "memory");
    else if (ahead == 1) asm volatile("s_waitcnt vmcnt(4)" ::: "memory");
    else                 asm volatile("s_waitcnt vmcnt(0)" ::: "memory");
    __builtin_amdgcn_s_barrier();

    const char* Abase = sm + (t & 3) * 32768;
    const char* Wbase = Abase + 16384;
    f16x8 af[2][2], wf[2][4];
#pragma unroll
    for (int kf = 0; kf < 2; ++kf) {
      const int ch = kf * 4 + g4;
#pragma unroll
      for (int m = 0; m < 2; ++m) {
        const int r = wr * 32 + m * 16 + col0;
        af[kf][m] = *(const f16x8*)(Abase + r * 128 + ((ch ^ (r & 7)) << 4));
      }
#pragma unroll
      for (int n = 0; n < 4; ++n) {
        const int r = wc * 64 + n * 16 + col0;
        wf[kf][n] = *(const f16x8*)(Wbase + r * 128 + ((ch ^ (r & 7)) << 4));
      }
    }
#pragma unroll
    for (int kf = 0; kf < 2; ++kf)
#pragma unroll
      for (int m = 0; m < 2; ++m)
#pragma unroll
        for (int n = 0; n < 4; ++n)
          acc[m][n] = __builtin_amdgcn_mfma_f32_16x16x32_f16(af[kf][m], wf[kf][n],
                                                             acc[m][n], 0, 0, 0);
  }

#pragma unroll
  for (int m = 0; m < 2; ++m)
#pragma unroll
    for (int n = 0; n < 4; ++n)
#pragma unroll
      for (int r = 0; r < 4; ++r) {
        const int b = bRow + wr * 32 + m * 16 + g4 * 4 + r;
        const int j = nBase + wc * 64 + n * 16 + col0;
        float v = acc[m][n][r] + p.bias[j];
        if (p.mode == M_TANH) {
          v = tanhf(v);
          const u16 hv = f2h(v);
          p.d0[(size_t)b * p.ld0 + j] = hv;
          if (p.d1) p.d1[(size_t)b * p.ld1 + j] = hv;
          if (p.c0) p.c0[(size_t)b * 1024 + j] = v;
          if (p.c1) p.c1[(size_t)b * 1024 + j] = v;
        } else if (p.mode == M_PLAIN) {
          p.d0[(size_t)b * p.ld0 + j] = f2h(v);
        } else {  // M_FC2: cols<512 plain -> d0; cols>=512 tanh -> d1
          if (j < 512) p.d0[(size_t)b * p.ld0 + j] = f2h(v);
          else         p.d1[(size_t)b * p.ld1 + (j - 512)] = f2h(tanhf(v));
        }
      }
}

// out projection: 128 blocks x 8 rows; wave owns 2 rows, lane a col pair.
__global__ __launch_bounds__(256, 4) void outk(const u16* A, const u16* W,
                                               const float* bias, u16* pdst,
                                               float* fout) {
  __shared__ __align__(16) u16 As[8][1024];
  const int tid = threadIdx.x;
  const int r0 = blockIdx.x * 8;
  const char* Ab = (const char*)A;
#pragma unroll
  for (int i = 0; i < 4; ++i) {
    const int s = i * 256 + tid;
    const int row = s >> 7, ch = s & 127;
    gll16(Ab + (size_t)(r0 + row) * 4096 + ch * 16, (char*)As + s * 16);
  }
  asm volatile("s_waitcnt vmcnt(0)" ::: "memory");
  __builtin_amdgcn_s_barrier();

  const int wid = tid >> 6, lane = tid & 63;
  const int c0 = lane * 2;
  if (c0 >= 90) return;
  const int row0 = wid * 2;
  const f16x8* a0 = (const f16x8*)As[row0];
  const f16x8* a1 = (const f16x8*)As[row0 + 1];
  const f16x8* w0 = (const f16x8*)(W + (size_t)c0 * 1024);
  const f16x8* w1 = (const f16x8*)(W + (size_t)(c0 + 1) * 1024);
  float acc00 = 0.f, acc01 = 0.f, acc10 = 0.f, acc11 = 0.f;
#pragma unroll 8
  for (int k = 0; k < 128; ++k) {
    const f16x8 wa = w0[k], wb = w1[k];
    const f16x8 aa = a0[k], ab = a1[k];
    acc00 = dot8(aa, wa, acc00);
    acc01 = dot8(aa, wb, acc01);
    acc10 = dot8(ab, wa, acc10);
    acc11 = dot8(ab, wb, acc11);
  }
  const float b0v = bias[c0], b1v = bias[c0 + 1];
  const int b0 = r0 + row0, b1 = b0 + 1;
  float v;
  v = acc00 + b0v;
  pdst[(size_t)b0 * 1664 + c0] = f2h(v);
  fout[(size_t)b0 * 5760 + c0] = sigm(v);
  v = acc01 + b1v;
  pdst[(size_t)b0 * 1664 + c0 + 1] = f2h(v);
  fout[(size_t)b0 * 5760 + c0 + 1] = sigm(v);
  v = acc10 + b0v;
  pdst[(size_t)b1 * 1664 + c0] = f2h(v);
  fout[(size_t)b1 * 5760 + c0] = sigm(v);
  v = acc11 + b1v;
  pdst[(size_t)b1 * 1664 + c0 + 1] = f2h(v);
  fout[(size_t)b1 * 5760 + c0 + 1] = sigm(v);
}

// ---- prologue kernels ----

// pack cell weights (f32 Wih/Whh) directly into fragment order:
// byte layout [by][t][wc][kf][n][lane]x16B; chunk ci -> 8 fp16 elems.
// gate-row g = (r>>5)*1024 + by*32 + (r&31), r = n*32 + wc*16 + (lane&15);
// k = t*64 + (kf*4 + (lane>>4))*8 + e  -- exactly what each lane's MFMA
// fragment consumed from LDS in the old kernel (layout-preserving).
struct FragP {
  u16* dst;
  const float* a; int Ka, sa;
  const float* b; int Kb, sb;
  int gap;
  int nt;  // K/64
};
__global__ void pack_frag(FragP f) {
  const long ci = (long)blockIdx.x * 256 + threadIdx.x;
  const long total = (long)512 * (f.nt * 64);
  if (ci >= total) return;
  const int lane = (int)(ci & 63);
  const int n = (int)((ci >> 6) & 3);
  const int kf = (int)((ci >> 8) & 1);
  const int wc = (int)((ci >> 9) & 1);
  const long r2 = ci >> 10;
  const int t = (int)(r2 % f.nt);
  const int by = (int)(r2 / f.nt);
  const int r = n * 32 + wc * 16 + (lane & 15);
  const int g = (r >> 5) * 1024 + by * 32 + (r & 31);
  const int k0 = t * 64 + (kf * 4 + (lane >> 4)) * 8;
  u16x8 out;
#pragma unroll
  for (int e = 0; e < 8; ++e) {
    const int k = k0 + e;
    float v = 0.f;
    if (k < f.Ka) v = f.a[(size_t)g * f.sa + k];
    else if (k >= f.Ka + f.gap && k < f.Ka + f.gap + f.Kb)
      v = f.b[(size_t)g * f.sb + (k - f.Ka - f.gap)];
    out[e] = f2h(v);
  }
  *(u16x8*)(f.dst + ci * 8) = out;
}

// row-major fp16 pack (non-cell weights)
__global__ void pack_w(u16* dst, const float* a, int Ka, const float* b, int Kb,
                       int gap, int Kp, int srcRows) {
  const int r = blockIdx.y;
  const int c = blockIdx.x * 256 + threadIdx.x;
  if (c >= Kp) return;
  float v = 0.f;
  if (r < srcRows) {
    if (c < Ka) v = a[(size_t)r * Ka + c];
    else if (c >= Ka + gap && c < Ka + gap + Kb) v = b[(size_t)r * Kb + (c - Ka - gap)];
  }
  dst[(size_t)r * Kp + c] = f2h(v);
}

__global__ void pack_fc1T(u16* dst, const float* src) {
  const int idx = blockIdx.x * 256 + threadIdx.x;
  const int n = idx >> 9, j = idx & 511;
  dst[idx] = f2h(src[(size_t)j * 1024 + n]);
}

__global__ __launch_bounds__(256, 4) void bias_fused(float* bfc2, const float* cfc_w,
                                                     const float* fc1_b,
                                                     const float* cfc_b) {
  const int i = blockIdx.x * 4 + (threadIdx.x >> 6);
  const int lane = threadIdx.x & 63;
  const float4* wrow = (const float4*)(cfc_w + (size_t)i * 512);
  const float4* bv = (const float4*)fc1_b;
  float s = 0.f;
#pragma unroll
  for (int q = 0; q < 2; ++q) {
    const float4 a = wrow[lane * 2 + q], b = bv[lane * 2 + q];
    s += a.x * b.x + a.y * b.y + a.z * b.z + a.w * b.w;
  }
#pragma unroll
  for (int off = 32; off; off >>= 1) s += __shfl_xor(s, off);
  if (lane == 0) bfc2[512 + i] = s + cfc_b[i];
}

struct BiasAll {
  float *bz, *bc0, *bc1, *bfc2, *bb0, *bb1, *bout, *bzero;
  const float *fzb, *ci0, *ch0, *ci1, *ch1, *f1b, *bi0, *bh0, *bi1, *bh1, *ob;
};
__global__ void pack_biases(BiasAll q) {
  int i = blockIdx.x * 256 + threadIdx.x;
  if (i < 1024) { q.bz[i] = q.fzb[i]; return; } i -= 1024;
  if (i < 4096) { q.bc0[i] = q.ci0[i] + q.ch0[i]; return; } i -= 4096;
  if (i < 4096) { q.bc1[i] = q.ci1[i] + q.ch1[i]; return; } i -= 4096;
  if (i < 512)  { q.bfc2[i] = q.f1b[i]; return; } i -= 512;
  if (i < 4096) { q.bb0[i] = q.bi0[i] + q.bh0[i]; return; } i -= 4096;
  if (i < 4096) { q.bb1[i] = q.bi1[i] + q.bh1[i]; return; } i -= 4096;
  if (i < 128)  { q.bout[i] = (i < 90) ? q.ob[i] : 0.f; return; } i -= 128;
  if (i < 1024) { q.bzero[i] = 0.f; }
}

__global__ void conv_h(u16* dst, const float* src, long n) {
  for (long i = (long)blockIdx.x * blockDim.x + threadIdx.x; i < n;
       i += (long)gridDim.x * blockDim.x)
    dst[i] = f2h(src[i]);
}

// zero Xc0 cols 0:512 (cond_in0) and Xb0 cols 512:640 (p slot + 38-col pad).
__global__ void zero_init(u32* xc0, u32* xb0) {
  const int i = blockIdx.x * 256 + threadIdx.x;
  if (i < 1024 * 256) {
    xc0[(i >> 8) * 768 + (i & 255)] = 0;
  } else {
    const int k = i - 1024 * 256;
    xb0[(k >> 6) * 832 + 256 + (k & 63)] = 0;
  }
}

extern "C" void kernel_launch(void* const* d_in, const int* in_sizes, int n_in,
                              void* d_out, int out_size, void* d_ws, size_t ws_size,
                              hipStream_t stream) {
  const float* z      = (const float*)d_in[0];
  const float* fc_z_w = (const float*)d_in[2];
  const float* fc_z_b = (const float*)d_in[3];
  const float* cWih0  = (const float*)d_in[4];
  const float* cWhh0  = (const float*)d_in[5];
  const float* cbih0  = (const float*)d_in[6];
  const float* cbhh0  = (const float*)d_in[7];
  const float* cWih1  = (const float*)d_in[8];
  const float* cWhh1  = (const float*)d_in[9];
  const float* cbih1  = (const float*)d_in[10];
  const float* cbhh1  = (const float*)d_in[11];
  const float* fc1_w  = (const float*)d_in[12];
  const float* fc1_b  = (const float*)d_in[13];
  const float* cfc_w  = (const float*)d_in[14];
  const float* cfc_b  = (const float*)d_in[15];
  const float* bWih0  = (const float*)d_in[16];
  const float* bWhh0  = (const float*)d_in[17];
  const float* bbih0  = (const float*)d_in[18];
  const float* bbhh0  = (const float*)d_in[19];
  const float* bWih1  = (const float*)d_in[20];
  const float* bWhh1  = (const float*)d_in[21];
  const float* bbih1  = (const float*)d_in[22];
  const float* bbhh1  = (const float*)d_in[23];
  const float* out_w  = (const float*)d_in[24];
  const float* out_b  = (const float*)d_in[25];
  float* outp = (float*)d_out;

  char* w = (char*)d_ws;
  auto alloc = [&](size_t bytes) {
    char* p = w;
    w += (bytes + 255) & ~(size_t)255;
    return p;
  };
  // fragged cell weights (same byte size as row-major)
  u16* Wc0f  = (u16*)alloc((size_t)4096 * 1536 * 2);
  u16* Wc1f  = (u16*)alloc((size_t)4096 * 2048 * 2);
  u16* Wb0f  = (u16*)alloc((size_t)4096 * 1664 * 2);
  u16* Wb1f  = (u16*)alloc((size_t)4096 * 2048 * 2);
  // row-major non-cell weights
  u16* Wz    = (u16*)alloc((size_t)1024 * 512 * 2);
  u16* Wfc2  = (u16*)alloc((size_t)1024 * 1024 * 2);
  u16* Wcfc  = (u16*)alloc((size_t)512 * 512 * 2);
  u16* fc1T  = (u16*)alloc((size_t)1024 * 512 * 2);
  u16* Wout  = (u16*)alloc((size_t)128 * 1024 * 2);
  u16* zh    = (u16*)alloc((size_t)1024 * 512 * 2);
  u16* Xc0   = (u16*)alloc((size_t)1024 * 1536 * 2);  // [cond_in 512 | h1 1024]
  u16* Xc1   = (u16*)alloc((size_t)1024 * 2048 * 2);  // [h1 | h2]
  u16* Xb0   = (u16*)alloc((size_t)1024 * 1664 * 2);  // [emb|p|pad|bh1]
  u16* Xb1   = (u16*)alloc((size_t)1024 * 2048 * 2);  // [bh1 | bh2]
  float* cc0  = (float*)alloc((size_t)1024 * 1024 * 4);
  float* cc1  = (float*)alloc((size_t)1024 * 1024 * 4);
  float* cbb0 = (float*)alloc((size_t)1024 * 1024 * 4);
  float* cbb1 = (float*)alloc((size_t)1024 * 1024 * 4);
  float* bz   = (float*)alloc(1024 * 4);
  float* bc0  = (float*)alloc(4096 * 4);
  float* bc1  = (float*)alloc(4096 * 4);
  float* bfc2 = (float*)alloc(1024 * 4);
  float* bb0  = (float*)alloc(4096 * 4);
  float* bb1  = (float*)alloc(4096 * 4);
  float* bout = (float*)alloc(128 * 4);
  float* bzero= (float*)alloc(1024 * 4);

  const dim3 blk(256), blk5(512);
  const dim3 gcell(256);

  // --- prologue ---
  {
    FragP f{Wc0f, cWih0, 512, 512, cWhh0, 1024, 1024, 0, 24};
    pack_frag<<<dim3(3072), blk, 0, stream>>>(f);
  }
  {
    FragP f{Wc1f, cWih1, 1024, 1024, cWhh1, 1024, 1024, 0, 32};
    pack_frag<<<dim3(4096), blk, 0, stream>>>(f);
  }
  {
    FragP f{Wb0f, bWih0, 602, 602, bWhh0, 1024, 1024, 38, 26};
    pack_frag<<<dim3(3328), blk, 0, stream>>>(f);
  }
  {
    FragP f{Wb1f, bWih1, 1024, 1024, bWhh1, 1024, 1024, 0, 32};
    pack_frag<<<dim3(4096), blk, 0, stream>>>(f);
  }
  pack_w<<<dim3(2, 1024), blk, 0, stream>>>(Wz,   fc_z_w, 512,  nullptr, 0, 0, 512,  1024);
  pack_w<<<dim3(4, 512),  blk, 0, stream>>>(Wfc2, fc1_w,  1024, nullptr, 0, 0, 1024, 512);
  pack_w<<<dim3(2, 512),  blk, 0, stream>>>(Wcfc, cfc_w,  512,  nullptr, 0, 0, 512,  512);
  pack_w<<<dim3(4, 128),  blk, 0, stream>>>(Wout, out_w,  1024, nullptr, 0, 0, 1024, 90);
  pack_fc1T<<<dim3(2048), blk, 0, stream>>>(fc1T, fc1_w);
  {
    BiasAll q{bz, bc0, bc1, bfc2, bb0, bb1, bout, bzero,
              fc_z_b, cbih0, cbhh0, cbih1, cbhh1, fc1_b,
              bbih0, bbhh0, bbih1, bbhh1, out_b};
    pack_biases<<<dim3(80), blk, 0, stream>>>(q);
  }
  bias_fused<<<dim3(128), blk, 0, stream>>>(bfc2, cfc_w, fc1_b, cfc_b);
  conv_h<<<dim3(512), blk, 0, stream>>>(zh, z, 1024L * 512);
  zero_init<<<dim3(1280), blk, 0, stream>>>((u32*)Xc0, (u32*)Xb0);
  {  // Wfused = cfc_w @ fc1_w -> Wfc2 rows 512:1024
    GemmP p{Wcfc, 512, fc1T, 512, 512, bzero, M_PLAIN,
            Wfc2 + (size_t)512 * 1024, 1024, nullptr, 0, nullptr, nullptr};
    gk<<<dim3(4, 8), blk5, 0, stream>>>(p);
  }
  {  // s0 = tanh(z @ Wz^T + bz) -> h1, h2 (fp16) and c1, c2 (f32)
    GemmP p{zh, 512, Wz, 512, 512, bz, M_TANH,
            Xc0 + 512, 1536, Xc1 + 1024, 2048, cc0, cc1};
    gk<<<dim3(8, 8), blk5, 0, stream>>>(p);
  }

  for (int t = 0; t < 16; ++t) {
    {  // conductor layer 0
      CellP p{Xc0, 1536, Wc0f, 24, 24, bc0, 0,
              Xc0 + 512, 1536, Xc1, 2048, cc0};
      ck<<<gcell, blk5, 0, stream>>>(p);
    }
    {  // conductor layer 1
      CellP p{Xc1, 2048, Wc1f, 32, 32, bc1, 0,
              Xc1 + 1024, 2048, nullptr, 0, cc1};
      ck<<<gcell, blk5, 0, stream>>>(p);
    }
    {  // fused fc1+cfc: cond_out -> Xc0 cols 0:512, tanh emb -> Xb0 cols 0:512
      GemmP p{Xc1 + 1024, 2048, Wfc2, 1024, 1024, bfc2, M_FC2,
              Xc0, 1536, Xb0, 1664, nullptr, nullptr};
      gk<<<dim3(8, 8), blk5, 0, stream>>>(p);
    }
    for (int s = 0; s < 4; ++s) {
      {  // bottom layer 0; s==0: bh1=0 & c=0 -> nt=10 (K=640), czero
        CellP p{Xb0, 1664, Wb0f, (s == 0) ? 10 : 26, 26, bb0, (s == 0),
                Xb0 + 640, 1664, Xb1, 2048, cbb0};
        ck<<<gcell, blk5, 0, stream>>>(p);
      }
      {  // bottom layer 1; s==0: bh2=0 & c=0 -> nt=16 (K=1024), czero
        CellP p{Xb1, 2048, Wb1f, (s == 0) ? 16 : 32, 32, bb1, (s == 0),
                Xb1 + 1024, 2048, nullptr, 0, cbb1};
        ck<<<gcell, blk5, 0, stream>>>(p);
      }
      // p = bh2 @ out_w^T + b ; p (fp16) -> Xb0 p-slot, sigmoid -> d_out
      outk<<<dim3(128), blk, 0, stream>>>(Xb1 + 1024, Wout, bout, Xb0 + 512,
                                          outp + (size_t)(t * 4 + s) * 90);
    }
  }
}